// Round 1
// baseline (1333.436 us; speedup 1.0000x reference)
//
#include <hip/hip_runtime.h>
#include <hip/hip_bf16.h>
#include <math.h>

// Problem: B=32, L1=512, L2=512, H=768
//   x_proj = relu(x @ W^T + b)   [B*L1, H]
//   y_proj = relu(y @ W^T + b)   [B*L2, H]
//   S      = x_proj @ y_proj^T per batch, masked with -inf
//   alpha  = softmax(S, axis=-1)
//   out    = alpha @ y per batch
//
// Round 0: correctness-first fp32 implementation. 64x64 LDS-tiled GEMMs,
// 4x4 micro-tile per thread, 256 threads/block.

#define BM 64
#define BN 64
#define BK 16

// C[M,N] = relu(A[M,K] @ W[N,K]^T + bias), K=768 fixed, N=768 fixed.
// Both A and W are K-contiguous (NT GEMM).
__global__ __launch_bounds__(256) void proj_relu_kernel(
    const float* __restrict__ A, const float* __restrict__ W,
    const float* __restrict__ bias, float* __restrict__ P) {
  __shared__ float As[BK][BM + 1];
  __shared__ float Ws[BK][BN + 1];
  const int K = 768;
  const int N = 768;
  int bm = blockIdx.x * BM;
  int bn = blockIdx.y * BN;
  int tid = threadIdx.x;
  int tx = tid & 15, ty = tid >> 4;
  int lr = tid >> 2;            // row 0..63 within tile
  int lk = (tid & 3) * 4;       // k offset 0..12

  float acc[4][4] = {};
  for (int k0 = 0; k0 < K; k0 += BK) {
    float4 a = *(const float4*)&A[(size_t)(bm + lr) * K + k0 + lk];
    float4 w = *(const float4*)&W[(size_t)(bn + lr) * K + k0 + lk];
    As[lk + 0][lr] = a.x; As[lk + 1][lr] = a.y;
    As[lk + 2][lr] = a.z; As[lk + 3][lr] = a.w;
    Ws[lk + 0][lr] = w.x; Ws[lk + 1][lr] = w.y;
    Ws[lk + 2][lr] = w.z; Ws[lk + 3][lr] = w.w;
    __syncthreads();
#pragma unroll
    for (int kk = 0; kk < BK; ++kk) {
      float av[4], wv[4];
#pragma unroll
      for (int i = 0; i < 4; ++i) av[i] = As[kk][ty * 4 + i];
#pragma unroll
      for (int j = 0; j < 4; ++j) wv[j] = Ws[kk][tx * 4 + j];
#pragma unroll
      for (int i = 0; i < 4; ++i)
#pragma unroll
        for (int j = 0; j < 4; ++j) acc[i][j] += av[i] * wv[j];
    }
    __syncthreads();
  }
#pragma unroll
  for (int i = 0; i < 4; ++i) {
    int m = bm + ty * 4 + i;
    int n0 = bn + tx * 4;
    float4 o;
    o.x = fmaxf(acc[i][0] + bias[n0 + 0], 0.f);
    o.y = fmaxf(acc[i][1] + bias[n0 + 1], 0.f);
    o.z = fmaxf(acc[i][2] + bias[n0 + 2], 0.f);
    o.w = fmaxf(acc[i][3] + bias[n0 + 3], 0.f);
    *(float4*)&P[(size_t)m * N + n0] = o;
  }
}

// Per-batch: S[b,m,n] = dot(Xp[b,m,:], Yp[b,n,:]) over K=768, with mask.
__global__ __launch_bounds__(256) void scores_kernel(
    const float* __restrict__ Xp, const float* __restrict__ Yp,
    const int* __restrict__ mask, float* __restrict__ S) {
  __shared__ float As[BK][BM + 1];
  __shared__ float Bs[BK][BN + 1];
  const int K = 768;
  const int L = 512;
  int b = blockIdx.z;
  const float* A = Xp + (size_t)b * L * K;
  const float* Bm = Yp + (size_t)b * L * K;
  const int* mk = mask + (size_t)b * L;
  float* Sb = S + (size_t)b * L * L;

  int bm = blockIdx.x * BM;
  int bn = blockIdx.y * BN;
  int tid = threadIdx.x;
  int tx = tid & 15, ty = tid >> 4;
  int lr = tid >> 2;
  int lk = (tid & 3) * 4;

  float acc[4][4] = {};
  for (int k0 = 0; k0 < K; k0 += BK) {
    float4 a = *(const float4*)&A[(size_t)(bm + lr) * K + k0 + lk];
    float4 w = *(const float4*)&Bm[(size_t)(bn + lr) * K + k0 + lk];
    As[lk + 0][lr] = a.x; As[lk + 1][lr] = a.y;
    As[lk + 2][lr] = a.z; As[lk + 3][lr] = a.w;
    Bs[lk + 0][lr] = w.x; Bs[lk + 1][lr] = w.y;
    Bs[lk + 2][lr] = w.z; Bs[lk + 3][lr] = w.w;
    __syncthreads();
#pragma unroll
    for (int kk = 0; kk < BK; ++kk) {
      float av[4], wv[4];
#pragma unroll
      for (int i = 0; i < 4; ++i) av[i] = As[kk][ty * 4 + i];
#pragma unroll
      for (int j = 0; j < 4; ++j) wv[j] = Bs[kk][tx * 4 + j];
#pragma unroll
      for (int i = 0; i < 4; ++i)
#pragma unroll
        for (int j = 0; j < 4; ++j) acc[i][j] += av[i] * wv[j];
    }
    __syncthreads();
  }
  int n0 = bn + tx * 4;
  float msk0 = mk[n0 + 0] ? -INFINITY : 0.f;
  float msk1 = mk[n0 + 1] ? -INFINITY : 0.f;
  float msk2 = mk[n0 + 2] ? -INFINITY : 0.f;
  float msk3 = mk[n0 + 3] ? -INFINITY : 0.f;
#pragma unroll
  for (int i = 0; i < 4; ++i) {
    int m = bm + ty * 4 + i;
    float4 o;
    o.x = acc[i][0] + msk0;   // x + (-inf) = -inf; x + 0 = x
    o.y = acc[i][1] + msk1;
    o.z = acc[i][2] + msk2;
    o.w = acc[i][3] + msk3;
    *(float4*)&Sb[(size_t)m * L + n0] = o;
  }
}

// Row softmax over 512 entries. One 256-thread block per row; in-place.
__global__ __launch_bounds__(256) void softmax_kernel(float* __restrict__ S) {
  size_t row = blockIdx.x;
  float* p = S + row * 512;
  int tid = threadIdx.x;
  int lane = tid & 63, wid = tid >> 6;
  float2 v = *(float2*)(p + tid * 2);

  float m = fmaxf(v.x, v.y);
#pragma unroll
  for (int off = 32; off > 0; off >>= 1) m = fmaxf(m, __shfl_down(m, off));
  __shared__ float redm[4];
  if (lane == 0) redm[wid] = m;
  __syncthreads();
  m = fmaxf(fmaxf(redm[0], redm[1]), fmaxf(redm[2], redm[3]));

  float e0 = __expf(v.x - m);   // exp(-inf - m) = 0 for masked entries
  float e1 = __expf(v.y - m);
  float s = e0 + e1;
#pragma unroll
  for (int off = 32; off > 0; off >>= 1) s += __shfl_down(s, off);
  __shared__ float reds[4];
  if (lane == 0) reds[wid] = s;
  __syncthreads();
  s = reds[0] + reds[1] + reds[2] + reds[3];
  float inv = 1.0f / s;
  *(float2*)(p + tid * 2) = make_float2(e0 * inv, e1 * inv);
}

// Per-batch: O[b,m,h] = sum_n alpha[b,m,n] * Y[b,n,h]. NN GEMM, K=512.
__global__ __launch_bounds__(256) void attn_out_kernel(
    const float* __restrict__ Alpha, const float* __restrict__ Y,
    float* __restrict__ O) {
  __shared__ float As[BK][BM + 1];
  __shared__ float Bs[BK][BN + 1];
  const int L = 512;   // K dim (n)
  const int H = 768;
  int b = blockIdx.z;
  const float* A = Alpha + (size_t)b * L * L;
  const float* Yb = Y + (size_t)b * L * H;
  float* Ob = O + (size_t)b * L * H;

  int bm = blockIdx.x * BM;   // m tile
  int bh = blockIdx.y * BN;   // h tile
  int tid = threadIdx.x;
  int tx = tid & 15, ty = tid >> 4;
  int lr = tid >> 2;           // A stage: row within m-tile
  int lk = (tid & 3) * 4;      // A stage: k offset
  int kr = tid >> 4;           // B stage: k row 0..15
  int hc = (tid & 15) * 4;     // B stage: h col offset

  float acc[4][4] = {};
  for (int k0 = 0; k0 < L; k0 += BK) {
    float4 a = *(const float4*)&A[(size_t)(bm + lr) * L + k0 + lk];
    As[lk + 0][lr] = a.x; As[lk + 1][lr] = a.y;
    As[lk + 2][lr] = a.z; As[lk + 3][lr] = a.w;
    float4 yv = *(const float4*)&Yb[(size_t)(k0 + kr) * H + bh + hc];
    Bs[kr][hc + 0] = yv.x; Bs[kr][hc + 1] = yv.y;
    Bs[kr][hc + 2] = yv.z; Bs[kr][hc + 3] = yv.w;
    __syncthreads();
#pragma unroll
    for (int kk = 0; kk < BK; ++kk) {
      float av[4], bv[4];
#pragma unroll
      for (int i = 0; i < 4; ++i) av[i] = As[kk][ty * 4 + i];
#pragma unroll
      for (int j = 0; j < 4; ++j) bv[j] = Bs[kk][tx * 4 + j];
#pragma unroll
      for (int i = 0; i < 4; ++i)
#pragma unroll
        for (int j = 0; j < 4; ++j) acc[i][j] += av[i] * bv[j];
    }
    __syncthreads();
  }
#pragma unroll
  for (int i = 0; i < 4; ++i) {
    int m = bm + ty * 4 + i;
    int h0 = bh + tx * 4;
    float4 o;
    o.x = acc[i][0]; o.y = acc[i][1]; o.z = acc[i][2]; o.w = acc[i][3];
    *(float4*)&Ob[(size_t)m * H + h0] = o;
  }
}

extern "C" void kernel_launch(void* const* d_in, const int* in_sizes, int n_in,
                              void* d_out, int out_size, void* d_ws, size_t ws_size,
                              hipStream_t stream) {
  const float* x = (const float*)d_in[0];       // [32,512,768]
  const float* y = (const float*)d_in[1];       // [32,512,768]
  const int* y_mask = (const int*)d_in[2];      // [32,512] bool->int
  const float* W = (const float*)d_in[3];       // [768,768] (out,in)
  const float* b = (const float*)d_in[4];       // [768]
  float* out = (float*)d_out;                   // [32,512,768]

  const size_t MP = (size_t)32 * 512 * 768;     // 12,582,912 elems
  float* xp = (float*)d_ws;                     // 50.3 MB
  float* yp = xp + MP;                          // 50.3 MB
  float* S = yp + MP;                           // 33.6 MB  (total 134 MB)

  dim3 blk(256);
  // Projections: M=16384, N=768
  proj_relu_kernel<<<dim3(16384 / BM, 768 / BN), blk, 0, stream>>>(x, W, b, xp);
  proj_relu_kernel<<<dim3(16384 / BM, 768 / BN), blk, 0, stream>>>(y, W, b, yp);
  // Scores: per-batch 512x512, K=768
  scores_kernel<<<dim3(512 / BM, 512 / BN, 32), blk, 0, stream>>>(xp, yp, y_mask, S);
  // Softmax over 16384 rows of 512
  softmax_kernel<<<dim3(32 * 512), blk, 0, stream>>>(S);
  // Output: per-batch 512x768, K=512
  attn_out_kernel<<<dim3(512 / BM, 768 / BN, 32), blk, 0, stream>>>(S, y, out);
}

// Round 2
// 449.933 us; speedup vs baseline: 2.9636x; 2.9636x over previous
//
#include <hip/hip_runtime.h>
#include <hip/hip_bf16.h>
#include <math.h>

// Problem: B=32, L1=512, L2=512, H=768
//   px  = relu(x @ W^T + b)   [16384, 768]  (split-bf16 MFMA, fp32 out)
//   py  = relu(y @ W^T + b)   [16384, 768]
//   S   = px @ py^T per batch, masked -inf  (split-bf16 MFMA)
//   a   = softmax(S) -> bf16
//   out = a @ y per batch                    (plain bf16 MFMA)
//
// Split-bf16: v = hi + lo (each bf16); A@B ~= Ah@Bh + Ah@Bl + Al@Bh
// (drop lo*lo, rel err ~2^-17) -> fp32-equivalent accuracy on the softmax
// logits, which is where bf16 noise would get amplified.

typedef short bf16x8 __attribute__((ext_vector_type(8)));
typedef float f32x4 __attribute__((ext_vector_type(4)));

#define LDP 40  // LDS row pitch in bf16 (32 data + 8 pad -> 2-way-free b128)

__device__ __forceinline__ short f2bf(float f) {
  union { float f; unsigned u; } c; c.f = f;
  unsigned r = c.u + 0x7fffu + ((c.u >> 16) & 1u);  // RNE
  return (short)(r >> 16);
}
__device__ __forceinline__ float bf2f(short s) {
  union { unsigned u; float f; } c; c.u = ((unsigned)(unsigned short)s) << 16;
  return c.f;
}
__device__ __forceinline__ void split4(const float4 v, short* ph, short* pl) {
  short h0 = f2bf(v.x), h1 = f2bf(v.y), h2 = f2bf(v.z), h3 = f2bf(v.w);
  ph[0] = h0; ph[1] = h1; ph[2] = h2; ph[3] = h3;
  pl[0] = f2bf(v.x - bf2f(h0)); pl[1] = f2bf(v.y - bf2f(h1));
  pl[2] = f2bf(v.z - bf2f(h2)); pl[3] = f2bf(v.w - bf2f(h3));
}

// ---------------- proj: P[M=16384,768] = relu(A @ W^T + bias), K=768 -------
__global__ __launch_bounds__(256) void proj_mfma_kernel(
    const float* __restrict__ A, const float* __restrict__ W,
    const float* __restrict__ bias, float* __restrict__ P) {
  const int K = 768, N = 768;
  __shared__ short Ah[128 * LDP], Al[128 * LDP], Bh[128 * LDP], Bl[128 * LDP];
  int bm = blockIdx.x * 128, bn = blockIdx.y * 128;
  int tid = threadIdx.x, lane = tid & 63, wave = tid >> 6;
  int wm = (wave & 1) * 64, wn = (wave >> 1) * 64;
  int fr = lane & 15, fk = (lane >> 4) * 8;

  f32x4 acc[4][4];
#pragma unroll
  for (int i = 0; i < 4; ++i)
#pragma unroll
    for (int j = 0; j < 4; ++j)
#pragma unroll
      for (int e = 0; e < 4; ++e) acc[i][j][e] = 0.f;

  for (int k0 = 0; k0 < K; k0 += 32) {
    __syncthreads();
#pragma unroll
    for (int i = 0; i < 4; ++i) {
      int f = tid + (i << 8);            // float4 id 0..1023
      int r = f >> 3, c = (f & 7) << 2;  // 128 rows x 32 cols
      float4 va = *(const float4*)&A[(size_t)(bm + r) * K + (k0 + c)];
      split4(va, &Ah[r * LDP + c], &Al[r * LDP + c]);
      float4 vb = *(const float4*)&W[(size_t)(bn + r) * K + (k0 + c)];
      split4(vb, &Bh[r * LDP + c], &Bl[r * LDP + c]);
    }
    __syncthreads();
    bf16x8 ah[4], al[4], bh[4], bl[4];
#pragma unroll
    for (int i = 0; i < 4; ++i) {
      ah[i] = *(const bf16x8*)&Ah[(wm + i * 16 + fr) * LDP + fk];
      al[i] = *(const bf16x8*)&Al[(wm + i * 16 + fr) * LDP + fk];
      bh[i] = *(const bf16x8*)&Bh[(wn + i * 16 + fr) * LDP + fk];
      bl[i] = *(const bf16x8*)&Bl[(wn + i * 16 + fr) * LDP + fk];
    }
#pragma unroll
    for (int i = 0; i < 4; ++i)
#pragma unroll
      for (int j = 0; j < 4; ++j) {
        acc[i][j] = __builtin_amdgcn_mfma_f32_16x16x32_bf16(al[i], bh[j], acc[i][j], 0, 0, 0);
        acc[i][j] = __builtin_amdgcn_mfma_f32_16x16x32_bf16(ah[i], bl[j], acc[i][j], 0, 0, 0);
        acc[i][j] = __builtin_amdgcn_mfma_f32_16x16x32_bf16(ah[i], bh[j], acc[i][j], 0, 0, 0);
      }
  }
#pragma unroll
  for (int i = 0; i < 4; ++i)
#pragma unroll
    for (int r = 0; r < 4; ++r) {
      int m = bm + wm + i * 16 + (lane >> 4) * 4 + r;
#pragma unroll
      for (int j = 0; j < 4; ++j) {
        int n = bn + wn + j * 16 + fr;
        float v = acc[i][j][r] + bias[n];
        P[(size_t)m * N + n] = fmaxf(v, 0.f);
      }
    }
}

// ---------------- scores: S[b,512,512] = px @ py^T, mask -inf, K=768 -------
__global__ __launch_bounds__(256) void scores_mfma_kernel(
    const float* __restrict__ Px, const float* __restrict__ Py,
    const int* __restrict__ mask, float* __restrict__ S) {
  const int K = 768, L = 512;
  __shared__ short Ah[128 * LDP], Al[128 * LDP], Bh[128 * LDP], Bl[128 * LDP];
  int b = blockIdx.z;
  const float* A = Px + (size_t)b * L * K;
  const float* Bm = Py + (size_t)b * L * K;
  const int* mk = mask + (size_t)b * L;
  float* Sb = S + (size_t)b * L * L;
  int bm = blockIdx.x * 128, bn = blockIdx.y * 128;
  int tid = threadIdx.x, lane = tid & 63, wave = tid >> 6;
  int wm = (wave & 1) * 64, wn = (wave >> 1) * 64;
  int fr = lane & 15, fk = (lane >> 4) * 8;

  f32x4 acc[4][4];
#pragma unroll
  for (int i = 0; i < 4; ++i)
#pragma unroll
    for (int j = 0; j < 4; ++j)
#pragma unroll
      for (int e = 0; e < 4; ++e) acc[i][j][e] = 0.f;

  for (int k0 = 0; k0 < K; k0 += 32) {
    __syncthreads();
#pragma unroll
    for (int i = 0; i < 4; ++i) {
      int f = tid + (i << 8);
      int r = f >> 3, c = (f & 7) << 2;
      float4 va = *(const float4*)&A[(size_t)(bm + r) * K + (k0 + c)];
      split4(va, &Ah[r * LDP + c], &Al[r * LDP + c]);
      float4 vb = *(const float4*)&Bm[(size_t)(bn + r) * K + (k0 + c)];
      split4(vb, &Bh[r * LDP + c], &Bl[r * LDP + c]);
    }
    __syncthreads();
    bf16x8 ah[4], al[4], bh[4], bl[4];
#pragma unroll
    for (int i = 0; i < 4; ++i) {
      ah[i] = *(const bf16x8*)&Ah[(wm + i * 16 + fr) * LDP + fk];
      al[i] = *(const bf16x8*)&Al[(wm + i * 16 + fr) * LDP + fk];
      bh[i] = *(const bf16x8*)&Bh[(wn + i * 16 + fr) * LDP + fk];
      bl[i] = *(const bf16x8*)&Bl[(wn + i * 16 + fr) * LDP + fk];
    }
#pragma unroll
    for (int i = 0; i < 4; ++i)
#pragma unroll
      for (int j = 0; j < 4; ++j) {
        acc[i][j] = __builtin_amdgcn_mfma_f32_16x16x32_bf16(al[i], bh[j], acc[i][j], 0, 0, 0);
        acc[i][j] = __builtin_amdgcn_mfma_f32_16x16x32_bf16(ah[i], bl[j], acc[i][j], 0, 0, 0);
        acc[i][j] = __builtin_amdgcn_mfma_f32_16x16x32_bf16(ah[i], bh[j], acc[i][j], 0, 0, 0);
      }
  }
#pragma unroll
  for (int i = 0; i < 4; ++i)
#pragma unroll
    for (int r = 0; r < 4; ++r) {
      int m = bm + wm + i * 16 + (lane >> 4) * 4 + r;
#pragma unroll
      for (int j = 0; j < 4; ++j) {
        int n = bn + wn + j * 16 + fr;
        float v = mk[n] ? -INFINITY : acc[i][j][r];
        Sb[(size_t)m * L + n] = v;
      }
    }
}

// ---------------- softmax rows of 512, fp32 in -> bf16 alpha out ----------
__global__ __launch_bounds__(256) void softmax_kernel(
    const float* __restrict__ S, short* __restrict__ Alpha) {
  size_t row = blockIdx.x;
  const float* p = S + row * 512;
  short* q = Alpha + row * 512;
  int tid = threadIdx.x, lane = tid & 63, wid = tid >> 6;
  float2 v = *(const float2*)(p + tid * 2);

  float m = fmaxf(v.x, v.y);
#pragma unroll
  for (int off = 32; off > 0; off >>= 1) m = fmaxf(m, __shfl_down(m, off));
  __shared__ float redm[4], reds[4];
  if (lane == 0) redm[wid] = m;
  __syncthreads();
  m = fmaxf(fmaxf(redm[0], redm[1]), fmaxf(redm[2], redm[3]));

  float e0 = __expf(v.x - m);
  float e1 = __expf(v.y - m);
  float s = e0 + e1;
#pragma unroll
  for (int off = 32; off > 0; off >>= 1) s += __shfl_down(s, off);
  if (lane == 0) reds[wid] = s;
  __syncthreads();
  s = reds[0] + reds[1] + reds[2] + reds[3];
  float inv = 1.0f / s;
  q[tid * 2] = f2bf(e0 * inv);
  q[tid * 2 + 1] = f2bf(e1 * inv);
}

// ---------------- attn: O[b,512,768] = alpha @ y, K=512, plain bf16 -------
__global__ __launch_bounds__(256) void attn_mfma_kernel(
    const short* __restrict__ Alpha, const float* __restrict__ Y,
    float* __restrict__ O) {
  const int L = 512, H = 768;
  __shared__ short As[128 * LDP], Bs[128 * LDP];
  int b = blockIdx.z;
  const short* Ab = Alpha + (size_t)b * L * L;
  const float* Yb = Y + (size_t)b * L * H;
  float* Ob = O + (size_t)b * L * H;
  int bm = blockIdx.x * 128, bn = blockIdx.y * 128;
  int tid = threadIdx.x, lane = tid & 63, wave = tid >> 6;
  int wm = (wave & 1) * 64, wn = (wave >> 1) * 64;
  int fr = lane & 15, fk = (lane >> 4) * 8;

  f32x4 acc[4][4];
#pragma unroll
  for (int i = 0; i < 4; ++i)
#pragma unroll
    for (int j = 0; j < 4; ++j)
#pragma unroll
      for (int e = 0; e < 4; ++e) acc[i][j][e] = 0.f;

  for (int k0 = 0; k0 < L; k0 += 32) {
    __syncthreads();
    // stage alpha tile [128 m][32 k] (already bf16, K-contiguous)
#pragma unroll
    for (int i = 0; i < 2; ++i) {
      int f = tid + (i << 8);            // short8 id 0..511
      int r = f >> 2, c = (f & 3) << 3;
      *(bf16x8*)&As[r * LDP + c] = *(const bf16x8*)&Ab[(size_t)(bm + r) * L + k0 + c];
    }
    // stage y tile [32 k][128 h] fp32, transposed into Bs[h][k] bf16
#pragma unroll
    for (int i = 0; i < 4; ++i) {
      int f = tid + (i << 8);            // float4 id 0..1023
      int kr = f >> 5, c = (f & 31) << 2;
      float4 v = *(const float4*)&Yb[(size_t)(k0 + kr) * H + bn + c];
      Bs[(c + 0) * LDP + kr] = f2bf(v.x);
      Bs[(c + 1) * LDP + kr] = f2bf(v.y);
      Bs[(c + 2) * LDP + kr] = f2bf(v.z);
      Bs[(c + 3) * LDP + kr] = f2bf(v.w);
    }
    __syncthreads();
    bf16x8 a[4], bb[4];
#pragma unroll
    for (int i = 0; i < 4; ++i) {
      a[i] = *(const bf16x8*)&As[(wm + i * 16 + fr) * LDP + fk];
      bb[i] = *(const bf16x8*)&Bs[(wn + i * 16 + fr) * LDP + fk];
    }
#pragma unroll
    for (int i = 0; i < 4; ++i)
#pragma unroll
      for (int j = 0; j < 4; ++j)
        acc[i][j] = __builtin_amdgcn_mfma_f32_16x16x32_bf16(a[i], bb[j], acc[i][j], 0, 0, 0);
  }
#pragma unroll
  for (int i = 0; i < 4; ++i)
#pragma unroll
    for (int r = 0; r < 4; ++r) {
      int m = bm + wm + i * 16 + (lane >> 4) * 4 + r;
#pragma unroll
      for (int j = 0; j < 4; ++j) {
        int h = bn + wn + j * 16 + fr;
        Ob[(size_t)m * H + h] = acc[i][j][r];
      }
    }
}

extern "C" void kernel_launch(void* const* d_in, const int* in_sizes, int n_in,
                              void* d_out, int out_size, void* d_ws, size_t ws_size,
                              hipStream_t stream) {
  const float* x = (const float*)d_in[0];   // [32,512,768]
  const float* y = (const float*)d_in[1];   // [32,512,768]
  const int* y_mask = (const int*)d_in[2];  // [32,512]
  const float* W = (const float*)d_in[3];   // [768,768]
  const float* b = (const float*)d_in[4];   // [768]
  float* out = (float*)d_out;               // [32,512,768]

  const size_t MP = (size_t)32 * 512 * 768;
  float* px = (float*)d_ws;       // 50.3 MB
  float* py = px + MP;            // 50.3 MB
  float* S = py + MP;             // 33.6 MB (total 134.2 MB)
  short* alpha = (short*)d_ws;    // 16.8 MB, overlays px (dead after scores)

  dim3 blk(256);
  proj_mfma_kernel<<<dim3(128, 6), blk, 0, stream>>>(x, W, b, px);
  proj_mfma_kernel<<<dim3(128, 6), blk, 0, stream>>>(y, W, b, py);
  scores_mfma_kernel<<<dim3(4, 4, 32), blk, 0, stream>>>(px, py, y_mask, S);
  softmax_kernel<<<dim3(32 * 512), blk, 0, stream>>>(S, alpha);
  attn_mfma_kernel<<<dim3(4, 6, 32), blk, 0, stream>>>(alpha, y, out);
}

// Round 3
// 407.955 us; speedup vs baseline: 3.2686x; 1.1029x over previous
//
#include <hip/hip_runtime.h>
#include <hip/hip_bf16.h>
#include <math.h>

// B=32, L1=L2=512, H=768.
//   Wh/Wl   = split-bf16 of W (precomputed once, lives in the future S region)
//   Pxh/Pxl = split-bf16 of relu(x@W^T+b)   (proj kernel, MFMA)
//   Pyh/Pyl = split-bf16 of relu(y@W^T+b)
//   S       = px@py^T per batch (3-MFMA split combo), mask -inf
//   alpha   = softmax(S) bf16               (overlays Pxh)
//   yT      = per-batch transposed bf16 y   (overlays Pyl)
//   out     = alpha @ y (plain bf16 MFMA)
//
// All-bf16 staging uses global_load_lds width=16 into unpadded 64B LDS rows
// (2-way bank aliasing is free). fp32->split uses truncation + v_perm pack
// (~3 VALU/float); dropped al*bl term keeps rel err ~2^-16.

typedef short bf16x8 __attribute__((ext_vector_type(8)));
typedef float f32x4 __attribute__((ext_vector_type(4)));

__device__ __forceinline__ void gld_lds16(const void* g, void* l) {
  __builtin_amdgcn_global_load_lds(
      (const __attribute__((address_space(1))) unsigned*)g,
      (__attribute__((address_space(3))) unsigned*)l, 16, 0, 0);
}

__device__ __forceinline__ short f2bf_rne(float f) {
  union { float f; unsigned u; } c; c.f = f;
  unsigned r = c.u + 0x7fffu + ((c.u >> 16) & 1u);
  return (short)(r >> 16);
}
__device__ __forceinline__ float bf2f(short s) {
  union { unsigned u; float f; } c; c.u = ((unsigned)(unsigned short)s) << 16;
  return c.f;
}
__device__ __forceinline__ float bfhi(float f) {
  union { float f; unsigned u; } c; c.f = f;
  c.u &= 0xffff0000u;
  return c.f;
}
// low short = top16(a), high short = top16(b)
__device__ __forceinline__ unsigned pack_trunc(float a, float b) {
  union { float f; unsigned u; } ca, cb; ca.f = a; cb.f = b;
  return __builtin_amdgcn_perm(cb.u, ca.u, 0x07060302u);
}

// ---------------- W split: fp32 [768x768] -> Wh, Wl bf16 (RNE) -------------
__global__ __launch_bounds__(256) void split_w_kernel(
    const float* __restrict__ W, short* __restrict__ Wh, short* __restrict__ Wl) {
  int idx = (blockIdx.x * 256 + threadIdx.x) * 4;
  float4 v = *(const float4*)&W[idx];
  short h[4], l[4];
  float vv[4] = {v.x, v.y, v.z, v.w};
#pragma unroll
  for (int j = 0; j < 4; ++j) {
    h[j] = f2bf_rne(vv[j]);
    l[j] = f2bf_rne(vv[j] - bf2f(h[j]));
  }
  *(uint2*)&Wh[idx] = *(uint2*)h;
  *(uint2*)&Wl[idx] = *(uint2*)l;
}

// ---- proj: Ph/Pl[16384,768] = split(relu(A @ W^T + b)), K=768, split MFMA --
__global__ __launch_bounds__(256) void proj_mfma_kernel(
    const float* __restrict__ A, const short* __restrict__ Wh,
    const short* __restrict__ Wl, const float* __restrict__ bias,
    short* __restrict__ Ph, short* __restrict__ Pl) {
  const int K = 768, N = 768;
  __shared__ short Ah[128 * 32], Al[128 * 32], Bh[128 * 32], Bl[128 * 32];
  int bm = blockIdx.x * 128, bn = blockIdx.y * 128;
  int tid = threadIdx.x, lane = tid & 63, wave = tid >> 6;
  int wm = (wave & 1) * 64, wn = (wave >> 1) * 64;
  int fr = lane & 15, fk = (lane >> 4) * 8;
  int lrow = lane >> 2, lcol = (lane & 3) << 3;   // glds: 4 lanes/row (64B)
  int sr = tid >> 3, sc = (tid & 7) << 2;         // A stage: 8 lanes/row fp32

  f32x4 acc[4][4];
#pragma unroll
  for (int i = 0; i < 4; ++i)
#pragma unroll
    for (int j = 0; j < 4; ++j)
#pragma unroll
      for (int e = 0; e < 4; ++e) acc[i][j][e] = 0.f;

  for (int k0 = 0; k0 < K; k0 += 32) {
    __syncthreads();
    // W tiles: pure async copy, wave w stages rows [w*32, w*32+32)
#pragma unroll
    for (int t = 0; t < 2; ++t) {
      int row = wave * 32 + t * 16;
      size_t g = (size_t)(bn + row + lrow) * K + k0 + lcol;
      gld_lds16(&Wh[g], &Bh[row * 32]);
      gld_lds16(&Wl[g], &Bl[row * 32]);
    }
    // A tile: fp32 -> trunc split (perm-packed)
#pragma unroll
    for (int i = 0; i < 4; ++i) {
      int r = sr + i * 32;
      float4 va = *(const float4*)&A[(size_t)(bm + r) * K + k0 + sc];
      uint2 hv, lv;
      hv.x = pack_trunc(va.x, va.y);
      hv.y = pack_trunc(va.z, va.w);
      lv.x = pack_trunc(va.x - bfhi(va.x), va.y - bfhi(va.y));
      lv.y = pack_trunc(va.z - bfhi(va.z), va.w - bfhi(va.w));
      *(uint2*)&Ah[r * 32 + sc] = hv;
      *(uint2*)&Al[r * 32 + sc] = lv;
    }
    __syncthreads();
    bf16x8 ah[4], al[4], bh[4], bl[4];
#pragma unroll
    for (int i = 0; i < 4; ++i) {
      ah[i] = *(const bf16x8*)&Ah[(wm + i * 16 + fr) * 32 + fk];
      al[i] = *(const bf16x8*)&Al[(wm + i * 16 + fr) * 32 + fk];
      bh[i] = *(const bf16x8*)&Bh[(wn + i * 16 + fr) * 32 + fk];
      bl[i] = *(const bf16x8*)&Bl[(wn + i * 16 + fr) * 32 + fk];
    }
#pragma unroll
    for (int i = 0; i < 4; ++i)
#pragma unroll
      for (int j = 0; j < 4; ++j) {
        acc[i][j] = __builtin_amdgcn_mfma_f32_16x16x32_bf16(al[i], bh[j], acc[i][j], 0, 0, 0);
        acc[i][j] = __builtin_amdgcn_mfma_f32_16x16x32_bf16(ah[i], bl[j], acc[i][j], 0, 0, 0);
        acc[i][j] = __builtin_amdgcn_mfma_f32_16x16x32_bf16(ah[i], bh[j], acc[i][j], 0, 0, 0);
      }
  }
#pragma unroll
  for (int i = 0; i < 4; ++i)
#pragma unroll
    for (int r = 0; r < 4; ++r) {
      int m = bm + wm + i * 16 + (lane >> 4) * 4 + r;
#pragma unroll
      for (int j = 0; j < 4; ++j) {
        int n = bn + wn + j * 16 + fr;
        float v = fmaxf(acc[i][j][r] + bias[n], 0.f);
        short hs = f2bf_rne(v);
        Ph[(size_t)m * N + n] = hs;
        Pl[(size_t)m * N + n] = f2bf_rne(v - bf2f(hs));
      }
    }
}

// ---- scores: S[b,512,512] = px@py^T (split MFMA), mask -inf, K=768 --------
__global__ __launch_bounds__(256) void scores_mfma_kernel(
    const short* __restrict__ Pxh, const short* __restrict__ Pxl,
    const short* __restrict__ Pyh, const short* __restrict__ Pyl,
    const int* __restrict__ mask, float* __restrict__ S) {
  const int K = 768, L = 512;
  __shared__ short Ah[128 * 32], Al[128 * 32], Bh[128 * 32], Bl[128 * 32];
  int b = blockIdx.z;
  size_t pb = (size_t)b * L * K;
  const int* mk = mask + (size_t)b * L;
  float* Sb = S + (size_t)b * L * L;
  int bm = blockIdx.x * 128, bn = blockIdx.y * 128;
  int tid = threadIdx.x, lane = tid & 63, wave = tid >> 6;
  int wm = (wave & 1) * 64, wn = (wave >> 1) * 64;
  int fr = lane & 15, fk = (lane >> 4) * 8;
  int lrow = lane >> 2, lcol = (lane & 3) << 3;

  f32x4 acc[4][4];
#pragma unroll
  for (int i = 0; i < 4; ++i)
#pragma unroll
    for (int j = 0; j < 4; ++j)
#pragma unroll
      for (int e = 0; e < 4; ++e) acc[i][j][e] = 0.f;

  for (int k0 = 0; k0 < K; k0 += 32) {
    __syncthreads();
#pragma unroll
    for (int t = 0; t < 2; ++t) {
      int row = wave * 32 + t * 16;
      size_t ga = pb + (size_t)(bm + row + lrow) * K + k0 + lcol;
      size_t gb = pb + (size_t)(bn + row + lrow) * K + k0 + lcol;
      gld_lds16(&Pxh[ga], &Ah[row * 32]);
      gld_lds16(&Pxl[ga], &Al[row * 32]);
      gld_lds16(&Pyh[gb], &Bh[row * 32]);
      gld_lds16(&Pyl[gb], &Bl[row * 32]);
    }
    __syncthreads();
    bf16x8 ah[4], al[4], bh[4], bl[4];
#pragma unroll
    for (int i = 0; i < 4; ++i) {
      ah[i] = *(const bf16x8*)&Ah[(wm + i * 16 + fr) * 32 + fk];
      al[i] = *(const bf16x8*)&Al[(wm + i * 16 + fr) * 32 + fk];
      bh[i] = *(const bf16x8*)&Bh[(wn + i * 16 + fr) * 32 + fk];
      bl[i] = *(const bf16x8*)&Bl[(wn + i * 16 + fr) * 32 + fk];
    }
#pragma unroll
    for (int i = 0; i < 4; ++i)
#pragma unroll
      for (int j = 0; j < 4; ++j) {
        acc[i][j] = __builtin_amdgcn_mfma_f32_16x16x32_bf16(al[i], bh[j], acc[i][j], 0, 0, 0);
        acc[i][j] = __builtin_amdgcn_mfma_f32_16x16x32_bf16(ah[i], bl[j], acc[i][j], 0, 0, 0);
        acc[i][j] = __builtin_amdgcn_mfma_f32_16x16x32_bf16(ah[i], bh[j], acc[i][j], 0, 0, 0);
      }
  }
#pragma unroll
  for (int i = 0; i < 4; ++i)
#pragma unroll
    for (int r = 0; r < 4; ++r) {
      int m = bm + wm + i * 16 + (lane >> 4) * 4 + r;
#pragma unroll
      for (int j = 0; j < 4; ++j) {
        int n = bn + wn + j * 16 + fr;
        Sb[(size_t)m * L + n] = mk[n] ? -INFINITY : acc[i][j][r];
      }
    }
}

// ---------------- softmax rows of 512, fp32 in -> bf16 alpha out ----------
__global__ __launch_bounds__(256) void softmax_kernel(
    const float* __restrict__ S, short* __restrict__ Alpha) {
  size_t row = blockIdx.x;
  const float* p = S + row * 512;
  short* q = Alpha + row * 512;
  int tid = threadIdx.x, lane = tid & 63, wid = tid >> 6;
  float2 v = *(const float2*)(p + tid * 2);

  float m = fmaxf(v.x, v.y);
#pragma unroll
  for (int off = 32; off > 0; off >>= 1) m = fmaxf(m, __shfl_down(m, off));
  __shared__ float redm[4], reds[4];
  if (lane == 0) redm[wid] = m;
  __syncthreads();
  m = fmaxf(fmaxf(redm[0], redm[1]), fmaxf(redm[2], redm[3]));

  float e0 = __expf(v.x - m);
  float e1 = __expf(v.y - m);
  float s = e0 + e1;
#pragma unroll
  for (int off = 32; off > 0; off >>= 1) s += __shfl_down(s, off);
  if (lane == 0) reds[wid] = s;
  __syncthreads();
  s = reds[0] + reds[1] + reds[2] + reds[3];
  float inv = 1.0f / s;
  q[tid * 2] = f2bf_rne(e0 * inv);
  q[tid * 2 + 1] = f2bf_rne(e1 * inv);
}

// -------- yT: y [b,512,768] fp32 -> yT [b,768,512] bf16 (RNE) -------------
__global__ __launch_bounds__(256) void yT_kernel(const float* __restrict__ Y,
                                                 short* __restrict__ YT) {
  __shared__ short T[64][65];
  int b = blockIdx.z;
  int n0 = blockIdx.x * 64, h0 = blockIdx.y * 64;
  const float* Yb = Y + (size_t)b * 512 * 768;
  short* Tb = YT + (size_t)b * 768 * 512;
  int tid = threadIdx.x;
  int r = tid >> 4, c = (tid & 15) << 2;
#pragma unroll
  for (int i = 0; i < 4; ++i) {
    int rr = r + i * 16;
    float4 v = *(const float4*)&Yb[(size_t)(n0 + rr) * 768 + h0 + c];
    T[c + 0][rr] = f2bf_rne(v.x);
    T[c + 1][rr] = f2bf_rne(v.y);
    T[c + 2][rr] = f2bf_rne(v.z);
    T[c + 3][rr] = f2bf_rne(v.w);
  }
  __syncthreads();
  int hr = tid >> 2, nc = (tid & 3) << 4;
  short* dst = &Tb[(size_t)(h0 + hr) * 512 + n0 + nc];
#pragma unroll
  for (int j = 0; j < 16; ++j) dst[j] = T[hr][nc + j];
}

// ---- attn: O[b,512,768] = alpha @ y, K=512, plain bf16 MFMA --------------
__global__ __launch_bounds__(256) void attn_mfma_kernel(
    const short* __restrict__ Alpha, const short* __restrict__ YT,
    float* __restrict__ O) {
  const int L = 512, H = 768;
  __shared__ short As[128 * 32], Bs[128 * 32];
  int b = blockIdx.z;
  const short* Ab = Alpha + (size_t)b * L * L;
  const short* Yb = YT + (size_t)b * H * L;
  float* Ob = O + (size_t)b * L * H;
  int bm = blockIdx.x * 128, bn = blockIdx.y * 128;
  int tid = threadIdx.x, lane = tid & 63, wave = tid >> 6;
  int wm = (wave & 1) * 64, wn = (wave >> 1) * 64;
  int fr = lane & 15, fk = (lane >> 4) * 8;
  int lrow = lane >> 2, lcol = (lane & 3) << 3;

  f32x4 acc[4][4];
#pragma unroll
  for (int i = 0; i < 4; ++i)
#pragma unroll
    for (int j = 0; j < 4; ++j)
#pragma unroll
      for (int e = 0; e < 4; ++e) acc[i][j][e] = 0.f;

  for (int k0 = 0; k0 < L; k0 += 32) {
    __syncthreads();
#pragma unroll
    for (int t = 0; t < 2; ++t) {
      int row = wave * 32 + t * 16;
      gld_lds16(&Ab[(size_t)(bm + row + lrow) * L + k0 + lcol], &As[row * 32]);
      gld_lds16(&Yb[(size_t)(bn + row + lrow) * L + k0 + lcol], &Bs[row * 32]);
    }
    __syncthreads();
    bf16x8 a[4], bb[4];
#pragma unroll
    for (int i = 0; i < 4; ++i) {
      a[i] = *(const bf16x8*)&As[(wm + i * 16 + fr) * 32 + fk];
      bb[i] = *(const bf16x8*)&Bs[(wn + i * 16 + fr) * 32 + fk];
    }
#pragma unroll
    for (int i = 0; i < 4; ++i)
#pragma unroll
      for (int j = 0; j < 4; ++j)
        acc[i][j] = __builtin_amdgcn_mfma_f32_16x16x32_bf16(a[i], bb[j], acc[i][j], 0, 0, 0);
  }
#pragma unroll
  for (int i = 0; i < 4; ++i)
#pragma unroll
    for (int r = 0; r < 4; ++r) {
      int m = bm + wm + i * 16 + (lane >> 4) * 4 + r;
#pragma unroll
      for (int j = 0; j < 4; ++j) {
        int h = bn + wn + j * 16 + fr;
        Ob[(size_t)m * H + h] = acc[i][j][r];
      }
    }
}

extern "C" void kernel_launch(void* const* d_in, const int* in_sizes, int n_in,
                              void* d_out, int out_size, void* d_ws, size_t ws_size,
                              hipStream_t stream) {
  const float* x = (const float*)d_in[0];   // [32,512,768]
  const float* y = (const float*)d_in[1];   // [32,512,768]
  const int* y_mask = (const int*)d_in[2];  // [32,512]
  const float* W = (const float*)d_in[3];   // [768,768]
  const float* b = (const float*)d_in[4];   // [768]
  float* out = (float*)d_out;               // [32,512,768]

  const size_t E = (size_t)16384 * 768;     // elems per split plane
  short* Pxh = (short*)d_ws;                // 25.2 MB
  short* Pxl = Pxh + E;                     // 25.2 MB
  short* Pyh = Pxl + E;                     // 25.2 MB
  short* Pyl = Pyh + E;                     // 25.2 MB
  float* S = (float*)(Pyl + E);             // 33.6 MB  (total exactly 128 MiB)
  short* Wh = (short*)S;                    // 1.2 MB, overlays S (dead before scores)
  short* Wl = Wh + 768 * 768;               // 1.2 MB
  short* alpha = Pxh;                       // overlays Pxh (dead after scores)
  short* yT = Pyl;                          // overlays Pyl (dead after scores)

  dim3 blk(256);
  split_w_kernel<<<dim3(576), blk, 0, stream>>>(W, Wh, Wl);
  proj_mfma_kernel<<<dim3(128, 6), blk, 0, stream>>>(x, Wh, Wl, b, Pxh, Pxl);
  proj_mfma_kernel<<<dim3(128, 6), blk, 0, stream>>>(y, Wh, Wl, b, Pyh, Pyl);
  scores_mfma_kernel<<<dim3(4, 4, 32), blk, 0, stream>>>(Pxh, Pxl, Pyh, Pyl, y_mask, S);
  yT_kernel<<<dim3(8, 12, 32), blk, 0, stream>>>(y, yT);
  softmax_kernel<<<dim3(32 * 512), blk, 0, stream>>>(S, alpha);
  attn_mfma_kernel<<<dim3(4, 6, 32), blk, 0, stream>>>(alpha, yT, out);
}

// Round 4
// 287.305 us; speedup vs baseline: 4.6412x; 1.4199x over previous
//
#include <hip/hip_runtime.h>
#include <hip/hip_bf16.h>
#include <math.h>

// B=32, L1=L2=512, H=768.  All-fp16 MFMA pipeline:
//   xh,yh,Wh = fp16(x), fp16(y), fp16(W)      (convert kernels, RNE)
//   Px = fp16(relu(xh@Wh^T+b)), Py likewise    (f16 MFMA, pure-glds staging)
//   S  = Px@Py^T per batch, mask -inf, fp32    (f16 MFMA)
//   alpha = fp16(softmax(S))                   (overlays xh)
//   yT = per-batch transpose of fp16(y)        (overlays Px)
//   out = alpha @ yT, fp32                     (f16 MFMA)
//
// fp16 input rounding gives logit noise ~0.006 std (vs 0.099 threshold) --
// no split needed. All GEMM staging is global_load_lds width=16 into
// unpadded 64B LDS rows (2-way bank aliasing free).

typedef _Float16 f16x8 __attribute__((ext_vector_type(8)));
typedef float f32x4 __attribute__((ext_vector_type(4)));

__device__ __forceinline__ void gld_lds16(const void* g, void* l) {
  __builtin_amdgcn_global_load_lds(
      (const __attribute__((address_space(1))) unsigned*)g,
      (__attribute__((address_space(3))) unsigned*)l, 16, 0, 0);
}

// ---------------- fp32 -> fp16 convert (8 elems/thread) --------------------
__global__ __launch_bounds__(256) void cvt_f16_kernel(
    const float* __restrict__ src, _Float16* __restrict__ dst) {
  size_t i = ((size_t)blockIdx.x * 256 + threadIdx.x) * 8;
  float4 a = *(const float4*)&src[i];
  float4 b = *(const float4*)&src[i + 4];
  _Float16 h[8] = {(_Float16)a.x, (_Float16)a.y, (_Float16)a.z, (_Float16)a.w,
                   (_Float16)b.x, (_Float16)b.y, (_Float16)b.z, (_Float16)b.w};
  *(uint4*)&dst[i] = *(uint4*)h;
}

// ---- proj: P[16384,768] = fp16(relu(A @ W^T + b)), K=768, NT fp16 GEMM ----
__global__ __launch_bounds__(256) void proj_mfma_kernel(
    const _Float16* __restrict__ A, const _Float16* __restrict__ W,
    const float* __restrict__ bias, _Float16* __restrict__ P) {
  const int K = 768, N = 768;
  __shared__ _Float16 As[128 * 32], Bs[128 * 32];
  int bm = blockIdx.x * 128, bn = blockIdx.y * 128;
  int tid = threadIdx.x, lane = tid & 63, wave = tid >> 6;
  int wm = (wave & 1) * 64, wn = (wave >> 1) * 64;
  int fr = lane & 15, fk = (lane >> 4) * 8;
  int lrow = lane >> 2, lcol = (lane & 3) << 3;

  f32x4 acc[4][4];
#pragma unroll
  for (int i = 0; i < 4; ++i)
#pragma unroll
    for (int j = 0; j < 4; ++j)
#pragma unroll
      for (int e = 0; e < 4; ++e) acc[i][j][e] = 0.f;

  for (int k0 = 0; k0 < K; k0 += 32) {
    __syncthreads();
#pragma unroll
    for (int t = 0; t < 2; ++t) {
      int row = wave * 32 + t * 16;
      gld_lds16(&A[(size_t)(bm + row + lrow) * K + k0 + lcol], &As[row * 32]);
      gld_lds16(&W[(size_t)(bn + row + lrow) * K + k0 + lcol], &Bs[row * 32]);
    }
    __syncthreads();
    f16x8 a[4], bb[4];
#pragma unroll
    for (int i = 0; i < 4; ++i) {
      a[i] = *(const f16x8*)&As[(wm + i * 16 + fr) * 32 + fk];
      bb[i] = *(const f16x8*)&Bs[(wn + i * 16 + fr) * 32 + fk];
    }
#pragma unroll
    for (int i = 0; i < 4; ++i)
#pragma unroll
      for (int j = 0; j < 4; ++j)
        acc[i][j] = __builtin_amdgcn_mfma_f32_16x16x32_f16(a[i], bb[j], acc[i][j], 0, 0, 0);
  }
#pragma unroll
  for (int i = 0; i < 4; ++i)
#pragma unroll
    for (int r = 0; r < 4; ++r) {
      int m = bm + wm + i * 16 + (lane >> 4) * 4 + r;
#pragma unroll
      for (int j = 0; j < 4; ++j) {
        int n = bn + wn + j * 16 + fr;
        P[(size_t)m * N + n] = (_Float16)fmaxf(acc[i][j][r] + bias[n], 0.f);
      }
    }
}

// ---- scores: S[b,512,512] = Px@Py^T fp32, mask -inf, K=768 ---------------
__global__ __launch_bounds__(256) void scores_mfma_kernel(
    const _Float16* __restrict__ Px, const _Float16* __restrict__ Py,
    const int* __restrict__ mask, float* __restrict__ S) {
  const int K = 768, L = 512;
  __shared__ _Float16 As[128 * 32], Bs[128 * 32];
  int b = blockIdx.z;
  size_t pb = (size_t)b * L * K;
  const int* mk = mask + (size_t)b * L;
  float* Sb = S + (size_t)b * L * L;
  int bm = blockIdx.x * 128, bn = blockIdx.y * 128;
  int tid = threadIdx.x, lane = tid & 63, wave = tid >> 6;
  int wm = (wave & 1) * 64, wn = (wave >> 1) * 64;
  int fr = lane & 15, fk = (lane >> 4) * 8;
  int lrow = lane >> 2, lcol = (lane & 3) << 3;

  f32x4 acc[4][4];
#pragma unroll
  for (int i = 0; i < 4; ++i)
#pragma unroll
    for (int j = 0; j < 4; ++j)
#pragma unroll
      for (int e = 0; e < 4; ++e) acc[i][j][e] = 0.f;

  for (int k0 = 0; k0 < K; k0 += 32) {
    __syncthreads();
#pragma unroll
    for (int t = 0; t < 2; ++t) {
      int row = wave * 32 + t * 16;
      gld_lds16(&Px[pb + (size_t)(bm + row + lrow) * K + k0 + lcol], &As[row * 32]);
      gld_lds16(&Py[pb + (size_t)(bn + row + lrow) * K + k0 + lcol], &Bs[row * 32]);
    }
    __syncthreads();
    f16x8 a[4], bb[4];
#pragma unroll
    for (int i = 0; i < 4; ++i) {
      a[i] = *(const f16x8*)&As[(wm + i * 16 + fr) * 32 + fk];
      bb[i] = *(const f16x8*)&Bs[(wn + i * 16 + fr) * 32 + fk];
    }
#pragma unroll
    for (int i = 0; i < 4; ++i)
#pragma unroll
      for (int j = 0; j < 4; ++j)
        acc[i][j] = __builtin_amdgcn_mfma_f32_16x16x32_f16(a[i], bb[j], acc[i][j], 0, 0, 0);
  }
#pragma unroll
  for (int i = 0; i < 4; ++i)
#pragma unroll
    for (int r = 0; r < 4; ++r) {
      int m = bm + wm + i * 16 + (lane >> 4) * 4 + r;
#pragma unroll
      for (int j = 0; j < 4; ++j) {
        int n = bn + wn + j * 16 + fr;
        Sb[(size_t)m * L + n] = mk[n] ? -INFINITY : acc[i][j][r];
      }
    }
}

// ---------------- softmax rows of 512, fp32 in -> fp16 alpha out ----------
__global__ __launch_bounds__(256) void softmax_kernel(
    const float* __restrict__ S, _Float16* __restrict__ Alpha) {
  size_t row = blockIdx.x;
  const float* p = S + row * 512;
  _Float16* q = Alpha + row * 512;
  int tid = threadIdx.x, lane = tid & 63, wid = tid >> 6;
  float2 v = *(const float2*)(p + tid * 2);

  float m = fmaxf(v.x, v.y);
#pragma unroll
  for (int off = 32; off > 0; off >>= 1) m = fmaxf(m, __shfl_down(m, off));
  __shared__ float redm[4], reds[4];
  if (lane == 0) redm[wid] = m;
  __syncthreads();
  m = fmaxf(fmaxf(redm[0], redm[1]), fmaxf(redm[2], redm[3]));

  float e0 = __expf(v.x - m);
  float e1 = __expf(v.y - m);
  float s = e0 + e1;
#pragma unroll
  for (int off = 32; off > 0; off >>= 1) s += __shfl_down(s, off);
  if (lane == 0) reds[wid] = s;
  __syncthreads();
  s = reds[0] + reds[1] + reds[2] + reds[3];
  float inv = 1.0f / s;
  q[tid * 2] = (_Float16)(e0 * inv);
  q[tid * 2 + 1] = (_Float16)(e1 * inv);
}

// -------- yT: y [b,512,768] fp32 -> yT [b,768,512] fp16 (RNE) -------------
__global__ __launch_bounds__(256) void yT_kernel(const float* __restrict__ Y,
                                                 _Float16* __restrict__ YT) {
  __shared__ _Float16 T[64][65];
  int b = blockIdx.z;
  int n0 = blockIdx.x * 64, h0 = blockIdx.y * 64;
  const float* Yb = Y + (size_t)b * 512 * 768;
  _Float16* Tb = YT + (size_t)b * 768 * 512;
  int tid = threadIdx.x;
  int r = tid >> 4, c = (tid & 15) << 2;
#pragma unroll
  for (int i = 0; i < 4; ++i) {
    int rr = r + i * 16;
    float4 v = *(const float4*)&Yb[(size_t)(n0 + rr) * 768 + h0 + c];
    T[c + 0][rr] = (_Float16)v.x;
    T[c + 1][rr] = (_Float16)v.y;
    T[c + 2][rr] = (_Float16)v.z;
    T[c + 3][rr] = (_Float16)v.w;
  }
  __syncthreads();
  int hr = tid >> 2, nc = (tid & 3) << 4;
  _Float16* dst = &Tb[(size_t)(h0 + hr) * 512 + n0 + nc];
  _Float16 tmp[16];
#pragma unroll
  for (int j = 0; j < 16; ++j) tmp[j] = T[hr][nc + j];
  *(uint4*)&dst[0] = *(uint4*)&tmp[0];
  *(uint4*)&dst[8] = *(uint4*)&tmp[8];
}

// ---- attn: O[b,512,768] = alpha @ y, K=512, fp16 MFMA --------------------
__global__ __launch_bounds__(256) void attn_mfma_kernel(
    const _Float16* __restrict__ Alpha, const _Float16* __restrict__ YT,
    float* __restrict__ O) {
  const int L = 512, H = 768;
  __shared__ _Float16 As[128 * 32], Bs[128 * 32];
  int b = blockIdx.z;
  const _Float16* Ab = Alpha + (size_t)b * L * L;
  const _Float16* Yb = YT + (size_t)b * H * L;
  float* Ob = O + (size_t)b * L * H;
  int bm = blockIdx.x * 128, bn = blockIdx.y * 128;
  int tid = threadIdx.x, lane = tid & 63, wave = tid >> 6;
  int wm = (wave & 1) * 64, wn = (wave >> 1) * 64;
  int fr = lane & 15, fk = (lane >> 4) * 8;
  int lrow = lane >> 2, lcol = (lane & 3) << 3;

  f32x4 acc[4][4];
#pragma unroll
  for (int i = 0; i < 4; ++i)
#pragma unroll
    for (int j = 0; j < 4; ++j)
#pragma unroll
      for (int e = 0; e < 4; ++e) acc[i][j][e] = 0.f;

  for (int k0 = 0; k0 < L; k0 += 32) {
    __syncthreads();
#pragma unroll
    for (int t = 0; t < 2; ++t) {
      int row = wave * 32 + t * 16;
      gld_lds16(&Ab[(size_t)(bm + row + lrow) * L + k0 + lcol], &As[row * 32]);
      gld_lds16(&Yb[(size_t)(bn + row + lrow) * L + k0 + lcol], &Bs[row * 32]);
    }
    __syncthreads();
    f16x8 a[4], bb[4];
#pragma unroll
    for (int i = 0; i < 4; ++i) {
      a[i] = *(const f16x8*)&As[(wm + i * 16 + fr) * 32 + fk];
      bb[i] = *(const f16x8*)&Bs[(wn + i * 16 + fr) * 32 + fk];
    }
#pragma unroll
    for (int i = 0; i < 4; ++i)
#pragma unroll
      for (int j = 0; j < 4; ++j)
        acc[i][j] = __builtin_amdgcn_mfma_f32_16x16x32_f16(a[i], bb[j], acc[i][j], 0, 0, 0);
  }
#pragma unroll
  for (int i = 0; i < 4; ++i)
#pragma unroll
    for (int r = 0; r < 4; ++r) {
      int m = bm + wm + i * 16 + (lane >> 4) * 4 + r;
#pragma unroll
      for (int j = 0; j < 4; ++j) {
        int h = bn + wn + j * 16 + fr;
        Ob[(size_t)m * H + h] = acc[i][j][r];
      }
    }
}

extern "C" void kernel_launch(void* const* d_in, const int* in_sizes, int n_in,
                              void* d_out, int out_size, void* d_ws, size_t ws_size,
                              hipStream_t stream) {
  const float* x = (const float*)d_in[0];   // [32,512,768]
  const float* y = (const float*)d_in[1];   // [32,512,768]
  const int* y_mask = (const int*)d_in[2];  // [32,512]
  const float* W = (const float*)d_in[3];   // [768,768]
  const float* b = (const float*)d_in[4];   // [768]
  float* out = (float*)d_out;               // [32,512,768]

  const size_t E = (size_t)16384 * 768;     // 12,582,912 elems / fp16 plane
  _Float16* xh = (_Float16*)d_ws;           // 25.2 MB
  _Float16* yh = xh + E;                    // 25.2 MB
  _Float16* Px = yh + E;                    // 25.2 MB
  _Float16* Py = Px + E;                    // 25.2 MB
  float* S = (float*)(Py + E);              // 33.6 MB  (total = 128 MiB)
  _Float16* Wh = (_Float16*)S;              // 1.2 MB, overlays S (dead before scores)
  _Float16* alpha = xh;                     // overlays xh (dead after proj)
  _Float16* yT = Px;                        // overlays Px (dead after scores)

  dim3 blk(256);
  cvt_f16_kernel<<<dim3(6144), blk, 0, stream>>>(x, xh);
  cvt_f16_kernel<<<dim3(6144), blk, 0, stream>>>(y, yh);
  cvt_f16_kernel<<<dim3(288), blk, 0, stream>>>(W, Wh);
  proj_mfma_kernel<<<dim3(128, 6), blk, 0, stream>>>(xh, Wh, b, Px);
  proj_mfma_kernel<<<dim3(128, 6), blk, 0, stream>>>(yh, Wh, b, Py);
  scores_mfma_kernel<<<dim3(4, 4, 32), blk, 0, stream>>>(Px, Py, y_mask, S);
  yT_kernel<<<dim3(8, 12, 32), blk, 0, stream>>>(y, yT);
  softmax_kernel<<<dim3(32 * 512), blk, 0, stream>>>(S, alpha);
  attn_mfma_kernel<<<dim3(4, 6, 32), blk, 0, stream>>>(alpha, yT, out);
}